// Round 1
// baseline (336.160 us; speedup 1.0000x reference)
//
#include <hip/hip_runtime.h>

#define DT 0.001f
#define TAU_SYN_INV 200.0f
#define V_TH 1.0f

// B,C,H,W = 16,64,128,128 ; N = 16777216 ; HW = 16384 elems = 4096 float4
__global__ __launch_bounds__(256) void trf_kernel(
    const float4* __restrict__ x,
    const float4* __restrict__ v0,
    const float4* __restrict__ i0,
    const float*  __restrict__ ps,
    float4* __restrict__ out_z,
    float4* __restrict__ out_v,
    float4* __restrict__ out_i,
    int n4)
{
    int i = blockIdx.x * blockDim.x + threadIdx.x;
    if (i >= n4) return;

    // channel = (element_idx / (H*W)) % C = (i4 / 4096) % 64
    const float dt_tau = DT * ps[(i >> 12) & 63];
    const float isyn_decay = 1.0f - DT * TAU_SYN_INV;   // 0.8

    const float4 v  = v0[i];
    const float4 c  = i0[i];
    const float4 xx = x[i];

    float4 z, vn, in_;

    {
        float vd = v.x + dt_tau * (c.x - v.x);
        bool spike = vd > V_TH;
        z.x  = spike ? 1.0f : 0.0f;
        vn.x = spike ? 0.0f : vd;
        in_.x = isyn_decay * c.x + xx.x;
    }
    {
        float vd = v.y + dt_tau * (c.y - v.y);
        bool spike = vd > V_TH;
        z.y  = spike ? 1.0f : 0.0f;
        vn.y = spike ? 0.0f : vd;
        in_.y = isyn_decay * c.y + xx.y;
    }
    {
        float vd = v.z + dt_tau * (c.z - v.z);
        bool spike = vd > V_TH;
        z.z  = spike ? 1.0f : 0.0f;
        vn.z = spike ? 0.0f : vd;
        in_.z = isyn_decay * c.z + xx.z;
    }
    {
        float vd = v.w + dt_tau * (c.w - v.w);
        bool spike = vd > V_TH;
        z.w  = spike ? 1.0f : 0.0f;
        vn.w = spike ? 0.0f : vd;
        in_.w = isyn_decay * c.w + xx.w;
    }

    out_z[i] = z;
    out_v[i] = vn;
    out_i[i] = in_;
}

extern "C" void kernel_launch(void* const* d_in, const int* in_sizes, int n_in,
                              void* d_out, int out_size, void* d_ws, size_t ws_size,
                              hipStream_t stream) {
    const float* x  = (const float*)d_in[0];
    const float* v0 = (const float*)d_in[1];
    const float* i0 = (const float*)d_in[2];
    const float* ps = (const float*)d_in[3];

    const int N  = in_sizes[0];          // 16777216
    const int n4 = N / 4;                // 4194304

    float* out = (float*)d_out;
    float4* out_z = (float4*)out;
    float4* out_v = (float4*)(out + (size_t)N);
    float4* out_i = (float4*)(out + 2 * (size_t)N);

    const int block = 256;
    const int grid  = (n4 + block - 1) / block;  // 16384 blocks

    trf_kernel<<<grid, block, 0, stream>>>(
        (const float4*)x, (const float4*)v0, (const float4*)i0, ps,
        out_z, out_v, out_i, n4);
}

// Round 3
// 323.500 us; speedup vs baseline: 1.0391x; 1.0391x over previous
//
#include <hip/hip_runtime.h>

#define DT 0.001f
#define TAU_SYN_INV 200.0f
#define V_TH 1.0f

// Native vector type — __builtin_nontemporal_* requires a true vector, not
// HIP's struct-based float4.
typedef float vfloat4 __attribute__((ext_vector_type(4)));

// B,C,H,W = 16,64,128,128 ; N = 16777216 ; HW = 16384 elems = 4096 float4
#define EPT 2

__global__ __launch_bounds__(256) void trf_kernel(
    const vfloat4* __restrict__ x,
    const vfloat4* __restrict__ v0,
    const vfloat4* __restrict__ i0,
    const float*   __restrict__ ps,
    vfloat4* __restrict__ out_z,
    vfloat4* __restrict__ out_v,
    vfloat4* __restrict__ out_i,
    int n4)
{
    const float isyn_decay = 1.0f - DT * TAU_SYN_INV;   // 0.8
    const int stride = gridDim.x * blockDim.x;
    int i = blockIdx.x * blockDim.x + threadIdx.x;

    #pragma unroll
    for (int it = 0; it < EPT; ++it, i += stride) {
        if (i >= n4) return;

        // channel = (elem / (H*W)) % C = (i4 / 4096) % 64 — wave-uniform
        const float dt_tau = DT * ps[(i >> 12) & 63];

        const vfloat4 v  = __builtin_nontemporal_load(&v0[i]);
        const vfloat4 c  = __builtin_nontemporal_load(&i0[i]);
        const vfloat4 xx = __builtin_nontemporal_load(&x[i]);

        vfloat4 z, vn, in_;

        #pragma unroll
        for (int k = 0; k < 4; ++k) {
            float vd = fmaf(dt_tau, c[k] - v[k], v[k]);
            bool s = vd > V_TH;
            z[k]   = s ? 1.0f : 0.0f;
            vn[k]  = s ? 0.0f : vd;
            in_[k] = fmaf(isyn_decay, c[k], xx[k]);
        }

        __builtin_nontemporal_store(z,   &out_z[i]);
        __builtin_nontemporal_store(vn,  &out_v[i]);
        __builtin_nontemporal_store(in_, &out_i[i]);
    }
}

extern "C" void kernel_launch(void* const* d_in, const int* in_sizes, int n_in,
                              void* d_out, int out_size, void* d_ws, size_t ws_size,
                              hipStream_t stream) {
    const float* x  = (const float*)d_in[0];
    const float* v0 = (const float*)d_in[1];
    const float* i0 = (const float*)d_in[2];
    const float* ps = (const float*)d_in[3];

    const int N  = in_sizes[0];          // 16777216
    const int n4 = N / 4;                // 4194304

    float* out = (float*)d_out;
    vfloat4* out_z = (vfloat4*)out;
    vfloat4* out_v = (vfloat4*)(out + (size_t)N);
    vfloat4* out_i = (vfloat4*)(out + 2 * (size_t)N);

    const int block = 256;
    const int grid  = (n4 + block * EPT - 1) / (block * EPT);  // 8192 blocks

    trf_kernel<<<grid, block, 0, stream>>>(
        (const vfloat4*)x, (const vfloat4*)v0, (const vfloat4*)i0, ps,
        out_z, out_v, out_i, n4);
}